// Round 9
// baseline (283.280 us; speedup 1.0000x reference)
//
#include <hip/hip_runtime.h>
#include <hip/hip_bf16.h>
#include <math.h>

#define D_MODEL 1024
#define NHEAD   16
#define HEAD_DIM 64
#define BATCH   4
#define SEQ     2048

typedef __attribute__((ext_vector_type(8))) short bf16x8;
typedef __attribute__((ext_vector_type(4))) float f32x4;
typedef __attribute__((ext_vector_type(16))) float f32x16;

__device__ inline ushort f2bf(float f) {
  __hip_bfloat16 h = __float2bfloat16(f);
  return *reinterpret_cast<ushort*>(&h);
}
__device__ inline uint pk2(float a, float b) {
  return (uint)f2bf(a) | ((uint)f2bf(b) << 16);
}
__device__ inline float bf2f(ushort u) {
  return __uint_as_float((uint)u << 16);
}
__device__ inline f32x16 zero16() {
  f32x16 z;
#pragma unroll
  for (int i = 0; i < 16; ++i) z[i] = 0.f;
  return z;
}
// raw v_exp_f32 (2^x), no denormal-guard wrapper (logits are O(1))
__device__ inline float fexp2(float x) { return __builtin_amdgcn_exp2f(x); }

// async 16B global -> LDS (dest = wave-uniform base + lane*16; LDS must be unpadded)
__device__ inline void gld_lds16(const ushort* g, ushort* l) {
  __builtin_amdgcn_global_load_lds(
      (const __attribute__((address_space(1))) void*)g,
      (__attribute__((address_space(3))) void*)l, 16, 0, 0);
}

// ---------------- diagnostic fill ----------------
__global__ __launch_bounds__(256) void fill_f32(float* __restrict__ p, int n, float v) {
  int i = blockIdx.x * 256 + threadIdx.x;
  if (i < n) p[i] = v;
}

// ---------------- x: fp32 -> bf16 (8 elems/thread) ----------------
__global__ __launch_bounds__(256) void cast_bf16(const float* __restrict__ in,
                                                 ushort* __restrict__ out, int n8) {
  int i = blockIdx.x * 256 + threadIdx.x;
  if (i >= n8) return;
  const float4* p = (const float4*)(in + i * 8);
  float4 a = p[0], b = p[1];
  uint4 o;
  o.x = pk2(a.x, a.y); o.y = pk2(a.z, a.w);
  o.z = pk2(b.x, b.y); o.w = pk2(b.z, b.w);
  ((uint4*)out)[i] = o;
}

// ---------------- fp32 -> bf16 transpose: in[R][C] f32 -> out[C][R] bf16 ----------------
__global__ __launch_bounds__(256) void transpose_f32_bf16(const float* __restrict__ in,
                                                          ushort* __restrict__ out,
                                                          int R, int C) {
  __shared__ float tile[32][33];
  int tx = threadIdx.x, ty = threadIdx.y;   // block (32,8)
  int c0 = blockIdx.x * 32, r0 = blockIdx.y * 32;
#pragma unroll
  for (int k = 0; k < 4; ++k)
    tile[ty + 8 * k][tx] = in[(size_t)(r0 + ty + 8 * k) * C + c0 + tx];
  __syncthreads();
#pragma unroll
  for (int k = 0; k < 4; ++k)
    out[(size_t)(c0 + ty + 8 * k) * R + r0 + tx] = f2bf(tile[tx][ty + 8 * k]);
}

// ---------------- 3-stage counted-vmcnt MFMA GEMM template ----------------
// C[M][N] = A[M][K] * BT[N][K]^T, bf16 in, OutT out. BK=64, 8 waves of 64x64.
// R8 (T4): R6/R7's per-tile `vmcnt(0)` was a full drain -- with stage issued only
// ~500cyc earlier and B L2-missing (R5: FETCH 86MB = B refetched ~11x), every tile
// stalled at L3/HBM latency. Now: 3 LDS stages, issue stage(t+2) per iter, wait
// `vmcnt(6)` (tile t+1's 6 loads stay in flight) -> each load gets ~2 K-tile
// periods (~2800cyc) to land. Drain to 0 only on the last tile.
// Race audit: buf b written@issue(t-2), read@t: per-wave vmcnt(6) BEFORE barrier(t)
// => all waves' t-loads landed. read(t) -> rewrite@issue(t+1) separated by barrier(t+1).
// Swizzle (R6, verified): byte ^= ((byte>>7)&7)<<4 involution; inverse on global
// source + forward on ds_read; gld_lds dest linear.
__device__ inline bf16x8 lds_read_swz(const ushort* base, int byteoff) {
  byteoff ^= ((byteoff >> 7) & 7) << 4;
  return *(const bf16x8*)((const char*)base + byteoff);
}

template <int BM, int BN, int WM, int WN, typename OutT>
__global__ __launch_bounds__(WM * WN * 64, 2) void gemm_sq(const ushort* __restrict__ A,
                                                           const ushort* __restrict__ BT,
                                                           OutT* __restrict__ C,
                                                           int M, int N, int K) {
  constexpr int THREADS = WM * WN * 64;
  constexpr int WR = BM / WM;           // per-wave rows (64)
  constexpr int WC = BN / WN;           // per-wave cols (64)
  constexpr int MT = WR / 16;
  constexpr int NTC = WC / 16;
  constexpr int MH = MT / 2;
  constexpr int NA = BM * 8 / THREADS;  // staging issues for A
  constexpr int NB = BN * 8 / THREADS;
  static_assert(NA + NB == 6, "vmcnt(6) literal assumes 6 issues per tile");

  __shared__ ushort AS[3][BM * 64];
  __shared__ ushort BS[3][BN * 64];

  const int tid = threadIdx.x;
  const int w = tid >> 6, lane = tid & 63;
  const int quad = lane >> 4, l16 = lane & 15;
  const int wm = w / WN, wn = w % WN;

  // T1: XCD-aware bijective swizzle (grids here: 768, 256 -- both %8==0)
  int bx = blockIdx.x, by = blockIdx.y;
  {
    int nwg = gridDim.x * gridDim.y;
    if ((nwg & 7) == 0) {
      int bid = by * gridDim.x + bx;
      int chunk = nwg >> 3;
      bid = (bid & 7) * chunk + (bid >> 3);
      bx = bid % gridDim.x;
      by = bid / gridDim.x;
    }
  }
  const int m0 = by * BM, n0 = bx * BN;

  f32x4 acc[MT][NTC];
#pragma unroll
  for (int mt = 0; mt < MT; ++mt)
#pragma unroll
    for (int nt = 0; nt < NTC; ++nt) acc[mt][nt] = (f32x4){0.f, 0.f, 0.f, 0.f};

  // staging maps: for linear LDS byte x, global source at inverse-swizzled s(x)
  const ushort* asrc[NA];
  const ushort* bsrc[NB];
  uint adst[NA], bdst[NB];
#pragma unroll
  for (int i = 0; i < NA; ++i) {
    int x = (i * THREADS + tid) * 16;
    int sx = x ^ (((x >> 7) & 7) << 4);
    asrc[i] = A + (size_t)(m0 + (sx >> 7)) * K + ((sx & 127) >> 1);
    adst[i] = (uint)(i * THREADS + w * 64) * 8;
  }
#pragma unroll
  for (int i = 0; i < NB; ++i) {
    int x = (i * THREADS + tid) * 16;
    int sx = x ^ (((x >> 7) & 7) << 4);
    bsrc[i] = BT + (size_t)(n0 + (sx >> 7)) * K + ((sx & 127) >> 1);
    bdst[i] = (uint)(i * THREADS + w * 64) * 8;
  }

  const int NKT = K >> 6;

  // prologue: issue stages 0 and 1
#pragma unroll
  for (int i = 0; i < NA; ++i) gld_lds16(asrc[i], AS[0] + adst[i]);
#pragma unroll
  for (int i = 0; i < NB; ++i) gld_lds16(bsrc[i], BS[0] + bdst[i]);
#pragma unroll
  for (int i = 0; i < NA; ++i) gld_lds16(asrc[i] + 64, AS[1] + adst[i]);
#pragma unroll
  for (int i = 0; i < NB; ++i) gld_lds16(bsrc[i] + 64, BS[1] + bdst[i]);

  for (int kt = 0; kt < NKT; ++kt) {
    const int cur = kt % 3;

    // counted wait: tile kt's 6 loads landed; tile kt+1's 6 may stay in flight
    if (kt == NKT - 1) asm volatile("s_waitcnt vmcnt(0)" ::: "memory");
    else               asm volatile("s_waitcnt vmcnt(6)" ::: "memory");
    __builtin_amdgcn_s_barrier();   // all waves' tile-kt loads landed; done with kt-1

    // ---- issue stage kt+2 (buffer (kt+2)%3 was read at kt-1, all waves past it)
    if (kt + 2 < NKT) {
      const int nx = (kt + 2) % 3;
      const int k0n = (kt + 2) << 6;
#pragma unroll
      for (int i = 0; i < NA; ++i) gld_lds16(asrc[i] + k0n, AS[nx] + adst[i]);
#pragma unroll
      for (int i = 0; i < NB; ++i) gld_lds16(bsrc[i] + k0n, BS[nx] + bdst[i]);
    }

    // ---- B fragments once per K-tile (reused by both phases)
    bf16x8 bfr[NTC][2];
#pragma unroll
    for (int nt = 0; nt < NTC; ++nt)
#pragma unroll
      for (int kk = 0; kk < 2; ++kk)
        bfr[nt][kk] = lds_read_swz(BS[cur], (wn * WC + nt * 16 + l16) * 128 + kk * 64 + quad * 16);

    // ---- two phases of A-rows
#pragma unroll
    for (int ph = 0; ph < 2; ++ph) {
      bf16x8 af[MH][2];
#pragma unroll
      for (int f = 0; f < MH; ++f)
#pragma unroll
        for (int kk = 0; kk < 2; ++kk)
          af[f][kk] = lds_read_swz(AS[cur],
              (wm * WR + (ph * MH + f) * 16 + l16) * 128 + kk * 64 + quad * 16);
      __builtin_amdgcn_s_setprio(1);
#pragma unroll
      for (int f = 0; f < MH; ++f)
#pragma unroll
        for (int nt = 0; nt < NTC; ++nt)
#pragma unroll
          for (int kk = 0; kk < 2; ++kk)
            acc[ph * MH + f][nt] = __builtin_amdgcn_mfma_f32_16x16x32_bf16(
                af[f][kk], bfr[nt][kk], acc[ph * MH + f][nt], 0, 0, 0);
      __builtin_amdgcn_s_setprio(0);
    }
  }

  // ---- epilogue
#pragma unroll
  for (int mt = 0; mt < MT; ++mt) {
#pragma unroll
    for (int nt = 0; nt < NTC; ++nt) {
#pragma unroll
      for (int r = 0; r < 4; ++r) {
        size_t idx = (size_t)(m0 + wm * WR + mt * 16 + quad * 4 + r) * N
                     + n0 + wn * WC + nt * 16 + l16;
        if constexpr (sizeof(OutT) == 4) C[idx] = acc[mt][nt][r];
        else                             C[idx] = f2bf(acc[mt][nt][r]);
      }
    }
  }
}

// ---------------- MFMA flash attention, 32x32x16 + in-register softmax ----------------
// (unchanged from R4 -- verified: absmax 1.95e-3, ~91.5 us, conflicts 0)
#define KST 72
#define VST 72
#define NT  (SEQ / 64)
__global__ __launch_bounds__(256, 4) void attn_mfma(const ushort* __restrict__ qkv,
                                                    ushort* __restrict__ attn_o) {
  __shared__ ushort Ks[2][64 * KST];     // K[key][d]
  __shared__ ushort VTs[2][64 * VST];    // V^T[d][key]

  const int tid = threadIdx.x;
  const int w = tid >> 6, lane = tid & 63;
  const int q32 = lane & 31, hi = lane >> 5;

  // XCD-chunked swizzle (bijective): all 16 q-blocks of a head on one XCD.
  const int f = blockIdx.x;
  const int xcd = f & 7;
  const int j = f >> 3;                  // 0..127
  const int qb = j & 15;
  const int hb = ((j >> 4) << 3) | xcd;  // 0..63
  const int h = hb & 15, b = hb >> 4;
  const int q0 = qb * 128;

  const float qscale = 0.125f * 1.44269504088896f;
  bf16x8 qfrag[4];
  {
    const ushort* qrow = qkv + (size_t)(b * SEQ + q0 + w * 32 + q32) * 3072 + h * 64;
#pragma unroll
    for (int dd = 0; dd < 4; ++dd) {
      bf16x8 fq = *(const bf16x8*)(qrow + dd * 16 + hi * 8);
#pragma unroll
      for (int jj = 0; jj < 8; ++jj)
        fq[jj] = (short)f2bf(bf2f((ushort)fq[jj]) * qscale);
      qfrag[dd] = fq;
    }
  }

  f32x16 oacc0 = zero16(), oacc1 = zero16(), lacc = zero16();

  bf16x8 ones;
#pragma unroll
  for (int jj = 0; jj < 8; ++jj) ones[jj] = (short)0x3F80;  // bf16 1.0

  const int sr = tid >> 2, sc = tid & 3;   // K: row sr, 16-col group sc
  const int kp = tid & 31, dg = tid >> 5;  // V: key pair kp, 8-d group dg

  const size_t kstep = (size_t)64 * 3072;
  const ushort* kbase = qkv + (size_t)(b * SEQ + sr) * 3072 + 1024 + h * 64 + sc * 16;
  const ushort* vbase = qkv + (size_t)(b * SEQ + 2 * kp) * 3072 + 2048 + h * 64 + dg * 8;

  // prologue: load tile 0 -> regs -> buf0 (loop-top barrier covers the writes)
  uint4 kreg0, kreg1, vreg0, vreg1;
  {
    const uint4* ks = (const uint4*)kbase;
    kreg0 = ks[0]; kreg1 = ks[1];
    vreg0 = *(const uint4*)vbase;
    vreg1 = *(const uint4*)(vbase + 3072);
    uint4* kdst = (uint4*)(Ks[0] + sr * KST + sc * 16);
    kdst[0] = kreg0; kdst[1] = kreg1;
    const ushort* ae = (const ushort*)&vreg0;
    const ushort* ce = (const ushort*)&vreg1;
#pragma unroll
    for (int jj = 0; jj < 8; ++jj) {
      VTs[0][(dg * 8 + jj) * VST + 2 * kp]     = ae[jj];
      VTs[0][(dg * 8 + jj) * VST + 2 * kp + 1] = ce[jj];
    }
  }

  for (int kt = 0; kt < NT; ++kt) {
    const int cur = kt & 1;
    __syncthreads();   // writes of buf[cur] (prev iter / prologue) complete

    // ---- prefetch issue: tile kt+1 -> regs (lands during QK+softmax+PV)
    if (kt + 1 < NT) {
      const uint4* ks = (const uint4*)(kbase + (size_t)(kt + 1) * kstep);
      kreg0 = ks[0]; kreg1 = ks[1];
      vreg0 = *(const uint4*)(vbase + (size_t)(kt + 1) * kstep);
      vreg1 = *(const uint4*)(vbase + (size_t)(kt + 1) * kstep + 3072);
    }

    // ---- QK^T (swapped), both 32-key halves first (ILP: SM0 can overlap QK1)
    f32x16 sacc0 = zero16(), sacc1 = zero16();
    __builtin_amdgcn_s_setprio(1);
#pragma unroll
    for (int dd = 0; dd < 4; ++dd) {
      bf16x8 kf0 = *(const bf16x8*)(Ks[cur] + (q32)*KST + dd * 16 + hi * 8);
      bf16x8 kf1 = *(const bf16x8*)(Ks[cur] + (32 + q32) * KST + dd * 16 + hi * 8);
      sacc0 = __builtin_amdgcn_mfma_f32_32x32x16_bf16(kf0, qfrag[dd], sacc0, 0, 0, 0);
      sacc1 = __builtin_amdgcn_mfma_f32_32x32x16_bf16(kf1, qfrag[dd], sacc1, 0, 0, 0);
    }
    __builtin_amdgcn_s_setprio(0);

    // ---- in-register softmax -> pa[kb2] PV A-fragments
    bf16x8 pa[4];
#pragma unroll
    for (int kblk = 0; kblk < 2; ++kblk) {
      const f32x16& sacc = kblk ? sacc1 : sacc0;
      uint d0[4], d1[4];
#pragma unroll
      for (int p = 0; p < 4; ++p) {
        d0[p] = pk2(fexp2(sacc[4 * p + 0]), fexp2(sacc[4 * p + 1]));
        d1[p] = pk2(fexp2(sacc[4 * p + 2]), fexp2(sacc[4 * p + 3]));
      }
      // permlane32_swap(A=d[2k2], B=d[2k2+1]) -> fr = {A0,A1,B0,B1} (traced R2)
#pragma unroll
      for (int k2 = 0; k2 < 2; ++k2) {
        uint A0 = d0[2 * k2], B0 = d0[2 * k2 + 1];
        uint A1 = d1[2 * k2], B1 = d1[2 * k2 + 1];
        asm("v_permlane32_swap_b32 %0, %1" : "+v"(A0), "+v"(B0));
        asm("v_permlane32_swap_b32 %0, %1" : "+v"(A1), "+v"(B1));
        uint4 fr = {A0, A1, B0, B1};
        pa[kblk * 2 + k2] = *(bf16x8*)&fr;
        lacc = __builtin_amdgcn_mfma_f32_32x32x16_bf16(pa[kblk * 2 + k2], ones, lacc, 0, 0, 0);
      }
    }

    // ---- O += P V : A = pa[kb2] (in regs), B = V^T rows -> V[key][d] frags
    __builtin_amdgcn_s_setprio(1);
#pragma unroll
    for (int kb2 = 0; kb2 < 4; ++kb2) {
      bf16x8 vf0 = *(const bf16x8*)(VTs[cur] + (q32)*VST + kb2 * 16 + hi * 8);
      bf16x8 vf1 = *(const bf16x8*)(VTs[cur] + (32 + q32) * VST + kb2 * 16 + hi * 8);
      oacc0 = __builtin_amdgcn_mfma_f32_32x32x16_bf16(pa[kb2], vf0, oacc0, 0, 0, 0);
      oacc1 = __builtin_amdgcn_mfma_f32_32x32x16_bf16(pa[kb2], vf1, oacc1, 0, 0, 0);
    }
    __builtin_amdgcn_s_setprio(0);

    // ---- stage-write: regs (tile kt+1) -> buf[cur^1]; overlaps other waves' PV.
    if (kt + 1 < NT) {
      uint4* kdst = (uint4*)(Ks[cur ^ 1] + sr * KST + sc * 16);
      kdst[0] = kreg0; kdst[1] = kreg1;
      const ushort* ae = (const ushort*)&vreg0;
      const ushort* ce = (const ushort*)&vreg1;
#pragma unroll
      for (int jj = 0; jj < 8; ++jj) {
        VTs[cur ^ 1][(dg * 8 + jj) * VST + 2 * kp]     = ae[jj];
        VTs[cur ^ 1][(dg * 8 + jj) * VST + 2 * kp + 1] = ce[jj];
      }
    }
  }

  // ---- epilogue: row = (reg&3) + 8*(reg>>2) + 4*hi, col = q32 (same layout for L)
#pragma unroll
  for (int p = 0; p < 4; ++p) {
#pragma unroll
    for (int r = 0; r < 4; ++r) {
      int qrow = r + 8 * p + 4 * hi;
      float linv = 1.0f / lacc[4 * p + r];
      ushort* orow = attn_o + (size_t)(b * SEQ + q0 + w * 32 + qrow) * 1024 + h * 64 + q32;
      orow[0]  = f2bf(oacc0[4 * p + r] * linv);
      orow[32] = f2bf(oacc1[4 * p + r] * linv);
    }
  }
}

extern "C" void kernel_launch(void* const* d_in, const int* in_sizes, int n_in,
                              void* d_out, int out_size, void* d_ws, size_t ws_size,
                              hipStream_t stream) {
  bool ok_n  = (n_in == 3);
  bool ok_s0 = ok_n && (in_sizes[0] == 4 * 2048 * 1024);
  bool ok_s1 = ok_n && (in_sizes[1] == 1024 * 3072);
  bool ok_s2 = ok_n && (in_sizes[2] == 1024 * 1024);
  bool ok_o  = (out_size == 4 * 2048 * 1024);
  bool ok_w  = (ws_size >= (size_t)8192 * 3072 * 4);
  if (!(ok_n && ok_s0 && ok_s1 && ok_s2 && ok_o && ok_w)) {
    float c = 64.0f + 1.0f * ok_n + 2.0f * ok_s0 + 4.0f * ok_s1 +
              8.0f * ok_s2 + 16.0f * ok_o + 32.0f * ok_w;
    fill_f32<<<(out_size + 255) / 256, 256, 0, stream>>>((float*)d_out, out_size, c);
    return;
  }

  const float* x     = (const float*)d_in[0];  // [8192][1024]
  const float* w_qkv = (const float*)d_in[1];  // [1024][3072]
  const float* w_out = (const float*)d_in[2];  // [1024][1024]

  char* ws = (char*)d_ws;
  ushort* qkv    = (ushort*)ws;                                  // 48 MB
  ushort* xb     = (ushort*)(ws + (size_t)48 * 1024 * 1024);     // 16 MB
  ushort* attn_o = (ushort*)(ws + (size_t)64 * 1024 * 1024);     // 16 MB
  ushort* wqkvT  = (ushort*)(ws + (size_t)80 * 1024 * 1024);     // 6 MB
  ushort* woutT  = (ushort*)(ws + (size_t)86 * 1024 * 1024);     // 2 MB

  cast_bf16<<<dim3(8192 * 1024 / 8 / 256), dim3(256), 0, stream>>>(x, xb, 8192 * 1024 / 8);
  transpose_f32_bf16<<<dim3(3072 / 32, 1024 / 32), dim3(32, 8), 0, stream>>>(w_qkv, wqkvT, 1024, 3072);
  transpose_f32_bf16<<<dim3(1024 / 32, 1024 / 32), dim3(32, 8), 0, stream>>>(w_out, woutT, 1024, 1024);

  // gemm1: 128x256 tile, 8 waves of 64x64, 3-stage pipeline -> grid 12x64 = 768
  gemm_sq<128, 256, 2, 4, ushort><<<dim3(3072 / 256, 8192 / 128), dim3(512), 0, stream>>>(
      xb, wqkvT, qkv, 8192, 3072, 1024);

  attn_mfma<<<dim3(1024), dim3(256), 0, stream>>>(qkv, attn_o);

  // gemm2: 256x128 tile, 8 waves of 64x64 -> grid 8x32 = 256 = exactly 1 block/CU
  gemm_sq<256, 128, 4, 2, float><<<dim3(1024 / 128, 8192 / 256), dim3(512), 0, stream>>>(
      attn_o, woutT, (float*)d_out, 8192, 1024, 1024);
}

// Round 10
// 278.704 us; speedup vs baseline: 1.0164x; 1.0164x over previous
//
#include <hip/hip_runtime.h>
#include <hip/hip_bf16.h>
#include <math.h>

#define D_MODEL 1024
#define NHEAD   16
#define HEAD_DIM 64
#define BATCH   4
#define SEQ     2048

typedef __attribute__((ext_vector_type(8))) short bf16x8;
typedef __attribute__((ext_vector_type(4))) float f32x4;
typedef __attribute__((ext_vector_type(16))) float f32x16;

__device__ inline ushort f2bf(float f) {
  __hip_bfloat16 h = __float2bfloat16(f);
  return *reinterpret_cast<ushort*>(&h);
}
__device__ inline uint pk2(float a, float b) {
  return (uint)f2bf(a) | ((uint)f2bf(b) << 16);
}
__device__ inline float bf2f(ushort u) {
  return __uint_as_float((uint)u << 16);
}
__device__ inline f32x16 zero16() {
  f32x16 z;
#pragma unroll
  for (int i = 0; i < 16; ++i) z[i] = 0.f;
  return z;
}
// raw v_exp_f32 (2^x), no denormal-guard wrapper (logits are O(1))
__device__ inline float fexp2(float x) { return __builtin_amdgcn_exp2f(x); }

// async 16B global -> LDS (dest = wave-uniform base + lane*16; LDS must be unpadded)
__device__ inline void gld_lds16(const ushort* g, ushort* l) {
  __builtin_amdgcn_global_load_lds(
      (const __attribute__((address_space(1))) void*)g,
      (__attribute__((address_space(3))) void*)l, 16, 0, 0);
}

// ---------------- diagnostic fill ----------------
__global__ __launch_bounds__(256) void fill_f32(float* __restrict__ p, int n, float v) {
  int i = blockIdx.x * 256 + threadIdx.x;
  if (i < n) p[i] = v;
}

// ---------------- x: fp32 -> bf16 (8 elems/thread) ----------------
__global__ __launch_bounds__(256) void cast_bf16(const float* __restrict__ in,
                                                 ushort* __restrict__ out, int n8) {
  int i = blockIdx.x * 256 + threadIdx.x;
  if (i >= n8) return;
  const float4* p = (const float4*)(in + i * 8);
  float4 a = p[0], b = p[1];
  uint4 o;
  o.x = pk2(a.x, a.y); o.y = pk2(a.z, a.w);
  o.z = pk2(b.x, b.y); o.w = pk2(b.z, b.w);
  ((uint4*)out)[i] = o;
}

// ---------------- fp32 -> bf16 transpose: in[R][C] f32 -> out[C][R] bf16 ----------------
__global__ __launch_bounds__(256) void transpose_f32_bf16(const float* __restrict__ in,
                                                          ushort* __restrict__ out,
                                                          int R, int C) {
  __shared__ float tile[32][33];
  int tx = threadIdx.x, ty = threadIdx.y;   // block (32,8)
  int c0 = blockIdx.x * 32, r0 = blockIdx.y * 32;
#pragma unroll
  for (int k = 0; k < 4; ++k)
    tile[ty + 8 * k][tx] = in[(size_t)(r0 + ty + 8 * k) * C + c0 + tx];
  __syncthreads();
#pragma unroll
  for (int k = 0; k < 4; ++k)
    out[(size_t)(c0 + ty + 8 * k) * R + r0 + tx] = f2bf(tile[tx][ty + 8 * k]);
}

// ---------------- 4-phase 256x256 MFMA GEMM (T3+T4), 8 waves of 128x64 ----------------
// C[M][N] = A[M][K] * BT[N][K]^T, bf16 in, OutT out. BK=64, NKT=K/64, grid-strided tiles.
// R9: quadrant-phased interleave (the piece R5-R8 lacked -- T4 counted waits are null
// without it, m218/m232). Per tile, 4 phases: ph1 read af0+bf0 | 16 MFMA; ph2 read af1
// | 16 MFMA; ph3 read bf1 | 16 MFMA, then barrier (all reads of buf[cur] done); ph4
// issue tile kt+2's 8 loads into buf[cur] (safe: previous occupant's reads barrier'd)
// | 16 pure-reg MFMA. Ledger: at each boundary outstanding = tiles kt (8) + kt+1 (8)
// -> `s_waitcnt vmcnt(8)` confirms kt with ~8 phases of load lead time; never 0
// mid-loop. 2 barriers/tile. Swizzle (R6-verified): byte ^= ((byte>>7)&7)<<4,
// inverse-applied on global source + forward on ds_read; gld_lds dest linear.
__device__ inline bf16x8 lds_read_swz(const ushort* base, int byteoff) {
  byteoff ^= ((byteoff >> 7) & 7) << 4;
  return *(const bf16x8*)((const char*)base + byteoff);
}

template <typename OutT>
__global__ __launch_bounds__(512, 2) void gemm_8ph(const ushort* __restrict__ A,
                                                   const ushort* __restrict__ BT,
                                                   OutT* __restrict__ C,
                                                   int M, int N, int K, int n_tiles) {
  __shared__ ushort AS[2][256 * 64];   // 32 KB per buf
  __shared__ ushort BS[2][256 * 64];   // 32 KB per buf  -> 128 KB total

  const int tid = threadIdx.x;
  const int w = tid >> 6, lane = tid & 63;
  const int quad = lane >> 4, l16 = lane & 15;
  const int wm = w >> 2, wn = w & 3;   // per-wave out: 128 rows x 64 cols
  const int tiles_x = N >> 8;
  const int NKT = K >> 6;

  // swizzled staging geometry (tile-independent part)
  int arow[4], acol[4];                // row within tile, k-element offset
  uint sdst[4];
#pragma unroll
  for (int i = 0; i < 4; ++i) {
    int x = (i * 512 + tid) * 16;
    int sx = x ^ (((x >> 7) & 7) << 4);
    arow[i] = sx >> 7;
    acol[i] = (sx & 127) >> 1;
    sdst[i] = (uint)(i * 512 + w * 64) * 8;
  }

  for (int t = blockIdx.x; t < n_tiles; t += gridDim.x) {
    const int m0 = (t / tiles_x) << 8, n0 = (t % tiles_x) << 8;

    int aoff[4], boff[4];
#pragma unroll
    for (int i = 0; i < 4; ++i) {
      aoff[i] = (m0 + arow[i]) * K + acol[i];
      boff[i] = (n0 + arow[i]) * K + acol[i];
    }

    f32x4 acc[8][4];
#pragma unroll
    for (int mt = 0; mt < 8; ++mt)
#pragma unroll
      for (int nt = 0; nt < 4; ++nt) acc[mt][nt] = (f32x4){0.f, 0.f, 0.f, 0.f};

    // prologue: issue tiles 0 and 1
#pragma unroll
    for (int i = 0; i < 4; ++i) gld_lds16(A + aoff[i], AS[0] + sdst[i]);
#pragma unroll
    for (int i = 0; i < 4; ++i) gld_lds16(BT + boff[i], BS[0] + sdst[i]);
#pragma unroll
    for (int i = 0; i < 4; ++i) gld_lds16(A + aoff[i] + 64, AS[1] + sdst[i]);
#pragma unroll
    for (int i = 0; i < 4; ++i) gld_lds16(BT + boff[i] + 64, BS[1] + sdst[i]);

    for (int kt = 0; kt < NKT; ++kt) {
      const int cur = kt & 1;

      // boundary: confirm tile kt (kt+1's 8 stay in flight mid-loop)
      if (kt + 1 < NKT) asm volatile("s_waitcnt vmcnt(8)" ::: "memory");
      else              asm volatile("s_waitcnt vmcnt(0)" ::: "memory");
      __builtin_amdgcn_s_barrier();

      bf16x8 af0[4][2], af1[4][2], bf0[2][2], bf1[2][2];

      // ---- ph1: rows 0-63 x cols 0-31
#pragma unroll
      for (int f = 0; f < 4; ++f)
#pragma unroll
        for (int kk = 0; kk < 2; ++kk)
          af0[f][kk] = lds_read_swz(AS[cur], (wm * 128 + f * 16 + l16) * 128 + kk * 64 + quad * 16);
#pragma unroll
      for (int g = 0; g < 2; ++g)
#pragma unroll
        for (int kk = 0; kk < 2; ++kk)
          bf0[g][kk] = lds_read_swz(BS[cur], (wn * 64 + g * 16 + l16) * 128 + kk * 64 + quad * 16);
      __builtin_amdgcn_s_setprio(1);
#pragma unroll
      for (int f = 0; f < 4; ++f)
#pragma unroll
        for (int g = 0; g < 2; ++g)
#pragma unroll
          for (int kk = 0; kk < 2; ++kk)
            acc[f][g] = __builtin_amdgcn_mfma_f32_16x16x32_bf16(af0[f][kk], bf0[g][kk], acc[f][g], 0, 0, 0);
      __builtin_amdgcn_s_setprio(0);

      // ---- ph2: rows 64-127 x cols 0-31
#pragma unroll
      for (int f = 0; f < 4; ++f)
#pragma unroll
        for (int kk = 0; kk < 2; ++kk)
          af1[f][kk] = lds_read_swz(AS[cur], (wm * 128 + 64 + f * 16 + l16) * 128 + kk * 64 + quad * 16);
      __builtin_amdgcn_s_setprio(1);
#pragma unroll
      for (int f = 0; f < 4; ++f)
#pragma unroll
        for (int g = 0; g < 2; ++g)
#pragma unroll
          for (int kk = 0; kk < 2; ++kk)
            acc[4 + f][g] = __builtin_amdgcn_mfma_f32_16x16x32_bf16(af1[f][kk], bf0[g][kk], acc[4 + f][g], 0, 0, 0);
      __builtin_amdgcn_s_setprio(0);

      // ---- ph3: rows 0-63 x cols 32-63
#pragma unroll
      for (int g = 0; g < 2; ++g)
#pragma unroll
        for (int kk = 0; kk < 2; ++kk)
          bf1[g][kk] = lds_read_swz(BS[cur], (wn * 64 + 32 + g * 16 + l16) * 128 + kk * 64 + quad * 16);
      __builtin_amdgcn_s_setprio(1);
#pragma unroll
      for (int f = 0; f < 4; ++f)
#pragma unroll
        for (int g = 0; g < 2; ++g)
#pragma unroll
          for (int kk = 0; kk < 2; ++kk)
            acc[f][2 + g] = __builtin_amdgcn_mfma_f32_16x16x32_bf16(af0[f][kk], bf1[g][kk], acc[f][2 + g], 0, 0, 0);
      __builtin_amdgcn_s_setprio(0);
      __builtin_amdgcn_s_barrier();   // all waves done reading buf[cur]

      // ---- ph4: issue tile kt+2 into buf[cur]; pure-reg MFMA rows 64-127 x cols 32-63
      if (kt + 2 < NKT) {
        const int k0n = (kt + 2) << 6;
#pragma unroll
        for (int i = 0; i < 4; ++i) gld_lds16(A + aoff[i] + k0n, AS[cur] + sdst[i]);
#pragma unroll
        for (int i = 0; i < 4; ++i) gld_lds16(BT + boff[i] + k0n, BS[cur] + sdst[i]);
      }
      __builtin_amdgcn_s_setprio(1);
#pragma unroll
      for (int f = 0; f < 4; ++f)
#pragma unroll
        for (int g = 0; g < 2; ++g)
#pragma unroll
          for (int kk = 0; kk < 2; ++kk)
            acc[4 + f][2 + g] = __builtin_amdgcn_mfma_f32_16x16x32_bf16(af1[f][kk], bf1[g][kk], acc[4 + f][2 + g], 0, 0, 0);
      __builtin_amdgcn_s_setprio(0);
    }

    // ---- epilogue
#pragma unroll
    for (int mt = 0; mt < 8; ++mt) {
#pragma unroll
      for (int nt = 0; nt < 4; ++nt) {
#pragma unroll
        for (int r = 0; r < 4; ++r) {
          size_t idx = (size_t)(m0 + wm * 128 + mt * 16 + quad * 4 + r) * N
                       + n0 + wn * 64 + nt * 16 + l16;
          if constexpr (sizeof(OutT) == 4) C[idx] = acc[mt][nt][r];
          else                             C[idx] = f2bf(acc[mt][nt][r]);
        }
      }
    }
  }
}

// ---------------- MFMA flash attention, 32x32x16 + in-register softmax ----------------
// (unchanged from R4 -- verified: absmax 1.95e-3, ~92-95 us, conflicts 0)
#define KST 72
#define VST 72
#define NT  (SEQ / 64)
__global__ __launch_bounds__(256, 4) void attn_mfma(const ushort* __restrict__ qkv,
                                                    ushort* __restrict__ attn_o) {
  __shared__ ushort Ks[2][64 * KST];     // K[key][d]
  __shared__ ushort VTs[2][64 * VST];    // V^T[d][key]

  const int tid = threadIdx.x;
  const int w = tid >> 6, lane = tid & 63;
  const int q32 = lane & 31, hi = lane >> 5;

  // XCD-chunked swizzle (bijective): all 16 q-blocks of a head on one XCD.
  const int f = blockIdx.x;
  const int xcd = f & 7;
  const int j = f >> 3;                  // 0..127
  const int qb = j & 15;
  const int hb = ((j >> 4) << 3) | xcd;  // 0..63
  const int h = hb & 15, b = hb >> 4;
  const int q0 = qb * 128;

  const float qscale = 0.125f * 1.44269504088896f;
  bf16x8 qfrag[4];
  {
    const ushort* qrow = qkv + (size_t)(b * SEQ + q0 + w * 32 + q32) * 3072 + h * 64;
#pragma unroll
    for (int dd = 0; dd < 4; ++dd) {
      bf16x8 fq = *(const bf16x8*)(qrow + dd * 16 + hi * 8);
#pragma unroll
      for (int jj = 0; jj < 8; ++jj)
        fq[jj] = (short)f2bf(bf2f((ushort)fq[jj]) * qscale);
      qfrag[dd] = fq;
    }
  }

  f32x16 oacc0 = zero16(), oacc1 = zero16(), lacc = zero16();

  bf16x8 ones;
#pragma unroll
  for (int jj = 0; jj < 8; ++jj) ones[jj] = (short)0x3F80;  // bf16 1.0

  const int sr = tid >> 2, sc = tid & 3;   // K: row sr, 16-col group sc
  const int kp = tid & 31, dg = tid >> 5;  // V: key pair kp, 8-d group dg

  const size_t kstep = (size_t)64 * 3072;
  const ushort* kbase = qkv + (size_t)(b * SEQ + sr) * 3072 + 1024 + h * 64 + sc * 16;
  const ushort* vbase = qkv + (size_t)(b * SEQ + 2 * kp) * 3072 + 2048 + h * 64 + dg * 8;

  // prologue: load tile 0 -> regs -> buf0 (loop-top barrier covers the writes)
  uint4 kreg0, kreg1, vreg0, vreg1;
  {
    const uint4* ks = (const uint4*)kbase;
    kreg0 = ks[0]; kreg1 = ks[1];
    vreg0 = *(const uint4*)vbase;
    vreg1 = *(const uint4*)(vbase + 3072);
    uint4* kdst = (uint4*)(Ks[0] + sr * KST + sc * 16);
    kdst[0] = kreg0; kdst[1] = kreg1;
    const ushort* ae = (const ushort*)&vreg0;
    const ushort* ce = (const ushort*)&vreg1;
#pragma unroll
    for (int jj = 0; jj < 8; ++jj) {
      VTs[0][(dg * 8 + jj) * VST + 2 * kp]     = ae[jj];
      VTs[0][(dg * 8 + jj) * VST + 2 * kp + 1] = ce[jj];
    }
  }

  for (int kt = 0; kt < NT; ++kt) {
    const int cur = kt & 1;
    __syncthreads();   // writes of buf[cur] (prev iter / prologue) complete

    // ---- prefetch issue: tile kt+1 -> regs (lands during QK+softmax+PV)
    if (kt + 1 < NT) {
      const uint4* ks = (const uint4*)(kbase + (size_t)(kt + 1) * kstep);
      kreg0 = ks[0]; kreg1 = ks[1];
      vreg0 = *(const uint4*)(vbase + (size_t)(kt + 1) * kstep);
      vreg1 = *(const uint4*)(vbase + (size_t)(kt + 1) * kstep + 3072);
    }

    // ---- QK^T (swapped), both 32-key halves first (ILP: SM0 can overlap QK1)
    f32x16 sacc0 = zero16(), sacc1 = zero16();
    __builtin_amdgcn_s_setprio(1);
#pragma unroll
    for (int dd = 0; dd < 4; ++dd) {
      bf16x8 kf0 = *(const bf16x8*)(Ks[cur] + (q32)*KST + dd * 16 + hi * 8);
      bf16x8 kf1 = *(const bf16x8*)(Ks[cur] + (32 + q32) * KST + dd * 16 + hi * 8);
      sacc0 = __builtin_amdgcn_mfma_f32_32x32x16_bf16(kf0, qfrag[dd], sacc0, 0, 0, 0);
      sacc1 = __builtin_amdgcn_mfma_f32_32x32x16_bf16(kf1, qfrag[dd], sacc1, 0, 0, 0);
    }
    __builtin_amdgcn_s_setprio(0);

    // ---- in-register softmax -> pa[kb2] PV A-fragments
    bf16x8 pa[4];
#pragma unroll
    for (int kblk = 0; kblk < 2; ++kblk) {
      const f32x16& sacc = kblk ? sacc1 : sacc0;
      uint d0[4], d1[4];
#pragma unroll
      for (int p = 0; p < 4; ++p) {
        d0[p] = pk2(fexp2(sacc[4 * p + 0]), fexp2(sacc[4 * p + 1]));
        d1[p] = pk2(fexp2(sacc[4 * p + 2]), fexp2(sacc[4 * p + 3]));
      }
      // permlane32_swap(A=d[2k2], B=d[2k2+1]) -> fr = {A0,A1,B0,B1} (traced R2)
#pragma unroll
      for (int k2 = 0; k2 < 2; ++k2) {
        uint A0 = d0[2 * k2], B0 = d0[2 * k2 + 1];
        uint A1 = d1[2 * k2], B1 = d1[2 * k2 + 1];
        asm("v_permlane32_swap_b32 %0, %1" : "+v"(A0), "+v"(B0));
        asm("v_permlane32_swap_b32 %0, %1" : "+v"(A1), "+v"(B1));
        uint4 fr = {A0, A1, B0, B1};
        pa[kblk * 2 + k2] = *(bf16x8*)&fr;
        lacc = __builtin_amdgcn_mfma_f32_32x32x16_bf16(pa[kblk * 2 + k2], ones, lacc, 0, 0, 0);
      }
    }

    // ---- O += P V : A = pa[kb2] (in regs), B = V^T rows -> V[key][d] frags
    __builtin_amdgcn_s_setprio(1);
#pragma unroll
    for (int kb2 = 0; kb2 < 4; ++kb2) {
      bf16x8 vf0 = *(const bf16x8*)(VTs[cur] + (q32)*VST + kb2 * 16 + hi * 8);
      bf16x8 vf1 = *(const bf16x8*)(VTs[cur] + (32 + q32) * VST + kb2 * 16 + hi * 8);
      oacc0 = __builtin_amdgcn_mfma_f32_32x32x16_bf16(pa[kb2], vf0, oacc0, 0, 0, 0);
      oacc1 = __builtin_amdgcn_mfma_f32_32x32x16_bf16(pa[kb2], vf1, oacc1, 0, 0, 0);
    }
    __builtin_amdgcn_s_setprio(0);

    // ---- stage-write: regs (tile kt+1) -> buf[cur^1]; overlaps other waves' PV.
    if (kt + 1 < NT) {
      uint4* kdst = (uint4*)(Ks[cur ^ 1] + sr * KST + sc * 16);
      kdst[0] = kreg0; kdst[1] = kreg1;
      const ushort* ae = (const ushort*)&vreg0;
      const ushort* ce = (const ushort*)&vreg1;
#pragma unroll
      for (int jj = 0; jj < 8; ++jj) {
        VTs[cur ^ 1][(dg * 8 + jj) * VST + 2 * kp]     = ae[jj];
        VTs[cur ^ 1][(dg * 8 + jj) * VST + 2 * kp + 1] = ce[jj];
      }
    }
  }

  // ---- epilogue: row = (reg&3) + 8*(reg>>2) + 4*hi, col = q32 (same layout for L)
#pragma unroll
  for (int p = 0; p < 4; ++p) {
#pragma unroll
    for (int r = 0; r < 4; ++r) {
      int qrow = r + 8 * p + 4 * hi;
      float linv = 1.0f / lacc[4 * p + r];
      ushort* orow = attn_o + (size_t)(b * SEQ + q0 + w * 32 + qrow) * 1024 + h * 64 + q32;
      orow[0]  = f2bf(oacc0[4 * p + r] * linv);
      orow[32] = f2bf(oacc1[4 * p + r] * linv);
    }
  }
}

extern "C" void kernel_launch(void* const* d_in, const int* in_sizes, int n_in,
                              void* d_out, int out_size, void* d_ws, size_t ws_size,
                              hipStream_t stream) {
  bool ok_n  = (n_in == 3);
  bool ok_s0 = ok_n && (in_sizes[0] == 4 * 2048 * 1024);
  bool ok_s1 = ok_n && (in_sizes[1] == 1024 * 3072);
  bool ok_s2 = ok_n && (in_sizes[2] == 1024 * 1024);
  bool ok_o  = (out_size == 4 * 2048 * 1024);
  bool ok_w  = (ws_size >= (size_t)8192 * 3072 * 4);
  if (!(ok_n && ok_s0 && ok_s1 && ok_s2 && ok_o && ok_w)) {
    float c = 64.0f + 1.0f * ok_n + 2.0f * ok_s0 + 4.0f * ok_s1 +
              8.0f * ok_s2 + 16.0f * ok_o + 32.0f * ok_w;
    fill_f32<<<(out_size + 255) / 256, 256, 0, stream>>>((float*)d_out, out_size, c);
    return;
  }

  const float* x     = (const float*)d_in[0];  // [8192][1024]
  const float* w_qkv = (const float*)d_in[1];  // [1024][3072]
  const float* w_out = (const float*)d_in[2];  // [1024][1024]

  char* ws = (char*)d_ws;
  ushort* qkv    = (ushort*)ws;                                  // 48 MB
  ushort* xb     = (ushort*)(ws + (size_t)48 * 1024 * 1024);     // 16 MB
  ushort* attn_o = (ushort*)(ws + (size_t)64 * 1024 * 1024);     // 16 MB
  ushort* wqkvT  = (ushort*)(ws + (size_t)80 * 1024 * 1024);     // 6 MB
  ushort* woutT  = (ushort*)(ws + (size_t)86 * 1024 * 1024);     // 2 MB

  cast_bf16<<<dim3(8192 * 1024 / 8 / 256), dim3(256), 0, stream>>>(x, xb, 8192 * 1024 / 8);
  transpose_f32_bf16<<<dim3(3072 / 32, 1024 / 32), dim3(32, 8), 0, stream>>>(w_qkv, wqkvT, 1024, 3072);
  transpose_f32_bf16<<<dim3(1024 / 32, 1024 / 32), dim3(32, 8), 0, stream>>>(w_out, woutT, 1024, 1024);

  // gemm1: 384 tiles of 256x256 on 192 blocks (2 tiles each, same B-column pair)
  gemm_8ph<ushort><<<dim3(192), dim3(512), 0, stream>>>(
      xb, wqkvT, qkv, 8192, 3072, 1024, 384);

  attn_mfma<<<dim3(1024), dim3(256), 0, stream>>>(qkv, attn_o);

  // gemm2: 128 tiles of 256x256 on 128 blocks
  gemm_8ph<float><<<dim3(128), dim3(512), 0, stream>>>(
      attn_o, woutT, (float*)d_out, 8192, 1024, 1024, 128);
}